// Round 1
// baseline (500.732 us; speedup 1.0000x reference)
//
#include <hip/hip_runtime.h>
#include <hip/hip_bf16.h>

// Problem constants
#define B_   4
#define NQ_  2048
#define NK_  2048
#define D_   1024
#define H_   16
#define DH_  64
#define SCALE_ 0.125f

typedef __attribute__((ext_vector_type(8))) __bf16 bf16x8;
typedef __attribute__((ext_vector_type(4))) float  f32x4;

typedef const __attribute__((address_space(1))) unsigned int* gas1p;
typedef __attribute__((address_space(3))) unsigned int*       las3p;

__device__ __forceinline__ f32x4 mfma16(bf16x8 a, bf16x8 b, f32x4 c) {
  return __builtin_amdgcn_mfma_f32_16x16x32_bf16(a, b, c, 0, 0, 0);
}
__device__ __forceinline__ void gload_lds16(const void* g, void* l) {
  __builtin_amdgcn_global_load_lds((gas1p)g, (las3p)l, 16, 0, 0);
}
__device__ __forceinline__ float nn_(float x) {
  if (__builtin_isnan(x)) return 0.0f;
  if (__builtin_isinf(x)) return x > 0.f ? 3.402823466e38f : -3.402823466e38f;
  return x;
}

// ---------------- fp32 -> bf16 convert (vectorized) ----------------
__global__ __launch_bounds__(256) void cvt_bf16_k(const float* __restrict__ s,
                                                  __bf16* __restrict__ d, int n) {
  int i = (blockIdx.x * blockDim.x + threadIdx.x) << 2;
  if (i >= n) return;
  float4 v = *(const float4*)(s + i);
  __bf16 o[4] __attribute__((aligned(8))) = {(__bf16)v.x, (__bf16)v.y, (__bf16)v.z, (__bf16)v.w};
  *(uint2*)(d + i) = *(uint2*)o;
}

// ------------- weight transpose + convert: src[K][N] -> dst[N][K] -------------
__global__ __launch_bounds__(256) void transpose_cvt_k(const float* __restrict__ src,
                                                       __bf16* __restrict__ dst,
                                                       int K, int N) {
  __shared__ float t[32][33];
  int n0 = blockIdx.x * 32, k0 = blockIdx.y * 32;
  int x = threadIdx.x, y0 = threadIdx.y;
  for (int yy = y0; yy < 32; yy += 8)
    t[yy][x] = src[(size_t)(k0 + yy) * N + n0 + x];
  __syncthreads();
  for (int yy = y0; yy < 32; yy += 8)
    dst[(size_t)(n0 + yy) * K + k0 + x] = (__bf16)t[x][yy];
}

// ---------------- m97-structure GEMM: C[M][N] = A[M][K] @ Bt[N][K]^T + bias ----------------
// 128x128 tile, BK=32, 4 waves (2x2), 4x4 16x16x32 fragments per wave.
template <bool OUT_BF16, bool RES>
__global__ __launch_bounds__(256) void gemm_bt_k(const __bf16* __restrict__ A,
                                                 const __bf16* __restrict__ Bt,
                                                 const float* __restrict__ bias,
                                                 const float* __restrict__ res,
                                                 void* __restrict__ out,
                                                 int M, int N, int K) {
  __shared__ __attribute__((aligned(16))) __bf16 As[128 * 32];
  __shared__ __attribute__((aligned(16))) __bf16 Bs[128 * 32];
  const int tid = threadIdx.x, lane = tid & 63, wid = tid >> 6;
  const int wr = wid >> 1, wc = wid & 1;
  const int g = lane >> 4, lr = lane & 15;
  const int m0 = blockIdx.y * 128, n0 = blockIdx.x * 128;

  const f32x4 zero4 = {0.f, 0.f, 0.f, 0.f};
  f32x4 acc[4][4];
#pragma unroll
  for (int m = 0; m < 4; m++)
#pragma unroll
    for (int n = 0; n < 4; n++) acc[m][n] = zero4;

  for (int k0 = 0; k0 < K; k0 += 32) {
    __syncthreads();  // previous iteration's LDS reads complete
#pragma unroll
    for (int i = 0; i < 2; i++) {
      int c = wid * 128 + i * 64 + lane;  // 16B chunk id in [0,512)
      gload_lds16(A + (size_t)(m0 + (c >> 2)) * K + k0 + ((c & 3) << 3),
                  (char*)As + wid * 2048 + i * 1024);
      gload_lds16(Bt + (size_t)(n0 + (c >> 2)) * K + k0 + ((c & 3) << 3),
                  (char*)Bs + wid * 2048 + i * 1024);
    }
    __syncthreads();  // staging drained (compiler emits vmcnt(0))

    bf16x8 af[4], bfv[4];
#pragma unroll
    for (int m = 0; m < 4; m++)
      af[m] = *(const bf16x8*)(As + (wr * 64 + m * 16 + lr) * 32 + g * 8);
#pragma unroll
    for (int n = 0; n < 4; n++)
      bfv[n] = *(const bf16x8*)(Bs + (wc * 64 + n * 16 + lr) * 32 + g * 8);
#pragma unroll
    for (int m = 0; m < 4; m++)
#pragma unroll
      for (int n = 0; n < 4; n++) acc[m][n] = mfma16(af[m], bfv[n], acc[m][n]);
  }

  // epilogue: C row = m0+wr*64+m*16+(lane>>4)*4+r ; col = n0+wc*64+n*16+(lane&15)
#pragma unroll
  for (int m = 0; m < 4; m++) {
    int row = m0 + wr * 64 + m * 16 + g * 4;
#pragma unroll
    for (int n = 0; n < 4; n++) {
      int col = n0 + wc * 64 + n * 16 + lr;
      float bv = bias[col];
#pragma unroll
      for (int r = 0; r < 4; r++) {
        size_t idx = (size_t)(row + r) * N + col;
        float v = acc[m][n][r] + bv;
        if (RES) v = nn_(v + res[idx]);
        if (OUT_BF16) ((__bf16*)out)[idx] = (__bf16)v;
        else          ((float*)out)[idx] = v;
      }
    }
  }
}

// ------------- per-head V transpose: KV_bf[B*NK][2048] -> Vt[(b*H+h)*64+d][NK] -------------
// Vt rows are chunk-swizzled per 128B tile-segment: chunk g holds source kk-chunk g^(d&7),
// so attention can stage linearly with global_load_lds and read swizzled (rule #21).
__global__ __launch_bounds__(256) void reorder_v_k(const __bf16* __restrict__ kv,
                                                   __bf16* __restrict__ vt) {
  __shared__ __attribute__((aligned(16))) __bf16 t[64][72];  // 144B stride (16B-aligned rows)
  int bh = blockIdx.y, b = bh >> 4, h = bh & 15;
  int kk0 = blockIdx.x * 64;
  int tid = threadIdx.x;
#pragma unroll
  for (int i = 0; i < 2; i++) {
    int c = tid + i * 256;          // 512 chunks of 8 bf16
    int kk = c >> 3, dc = c & 7;
    const __bf16* src = kv + (size_t)(b * NK_ + kk0 + kk) * 2048 + 1024 + h * 64 + dc * 8;
    *(float4*)&t[kk][dc * 8] = *(const float4*)src;
  }
  __syncthreads();
#pragma unroll
  for (int i = 0; i < 2; i++) {
    int c = tid + i * 256;
    int d = c >> 3, gch = c & 7;
    int s = gch ^ (d & 7);
    __bf16 tmp[8] __attribute__((aligned(16)));
#pragma unroll
    for (int j = 0; j < 8; j++) tmp[j] = t[s * 8 + j][d];
    __bf16* dst = vt + ((size_t)bh * 64 + d) * (size_t)NK_ + kk0 + gch * 8;
    *(float4*)dst = *(float4*)tmp;
  }
}

// ---------------- flash attention ----------------
// grid: (NQ/64, B*H), 256 threads (4 waves x 16 q-rows). KVBLK=64.
// Kt LDS [kk][64d] swizzled byte^=((kk&7)<<4) via pre-swizzled per-lane global src.
// Vl LDS [d][64kk] swizzled byte^=((d&7)<<4) (pre-applied in Vt global layout).
// P per-wave LDS [16q][64kk] swizzled byte^=(((q>>2)&3)<<4).
__global__ __launch_bounds__(256) void attn_k(const __bf16* __restrict__ Qg,
                                              const __bf16* __restrict__ KVg,
                                              const __bf16* __restrict__ Vt,
                                              __bf16* __restrict__ AO) {
  __shared__ __attribute__((aligned(16))) __bf16 Kt[64 * 64];
  __shared__ __attribute__((aligned(16))) __bf16 Vl[64 * 64];
  __shared__ __attribute__((aligned(16))) __bf16 Pl[4][16 * 64];
  const int tid = threadIdx.x, lane = tid & 63, wid = tid >> 6;
  const int g = lane >> 4, lr = lane & 15;
  const int bh = blockIdx.y, b = bh >> 4, h = bh & 15;
  const int qbase = blockIdx.x * 64 + wid * 16;

  // Q fragments (A-operand): row = qbase+lr, d = ds*32 + g*8 .. +8
  bf16x8 qf[2];
  {
    const __bf16* qp = Qg + ((size_t)(b * NQ_ + qbase + lr)) * 1024 + h * 64 + g * 8;
    qf[0] = *(const bf16x8*)qp;
    qf[1] = *(const bf16x8*)(qp + 32);
  }

  const f32x4 zero4 = {0.f, 0.f, 0.f, 0.f};
  f32x4 po[4];
#pragma unroll
  for (int df = 0; df < 4; df++) po[df] = zero4;
  float mrow[4], lrow[4];
#pragma unroll
  for (int r = 0; r < 4; r++) { mrow[r] = -1e30f; lrow[r] = 0.f; }

  for (int kv0 = 0; kv0 < NK_; kv0 += 64) {
    __syncthreads();  // previous tile's LDS reads done
    // stage K (pre-swizzled per-lane source) and V (swizzle pre-applied in Vt)
#pragma unroll
    for (int i = 0; i < 2; i++) {
      int c = wid * 128 + i * 64 + lane;  // chunk in [0,512)
      int kk = c >> 3, cc = c & 7;
      const __bf16* ks = KVg + (size_t)(b * NK_ + kv0 + kk) * 2048 + h * 64 + ((cc ^ (kk & 7)) << 3);
      gload_lds16(ks, (char*)Kt + wid * 2048 + i * 1024);
      const __bf16* vs = Vt + ((size_t)bh * 64 + kk) * (size_t)NK_ + kv0 + (cc << 3);
      gload_lds16(vs, (char*)Vl + wid * 2048 + i * 1024);
    }
    __syncthreads();  // staging drained

    // S = Q K^T  (raw, scale applied later)
    f32x4 sa[4];
#pragma unroll
    for (int n = 0; n < 4; n++) sa[n] = zero4;
#pragma unroll
    for (int n = 0; n < 4; n++) {
#pragma unroll
      for (int ds = 0; ds < 2; ds++) {
        int kk = n * 16 + lr;
        bf16x8 kf = *(const bf16x8*)((const char*)Kt + kk * 128 + ((ds * 64 + g * 16) ^ ((kk & 7) << 4)));
        sa[n] = mfma16(qf[ds], kf, sa[n]);
      }
    }

    // online softmax (row q = g*4+r lives in the 16 lanes of group g)
    float alpha[4];
#pragma unroll
    for (int r = 0; r < 4; r++) {
      float v = fmaxf(fmaxf(sa[0][r], sa[1][r]), fmaxf(sa[2][r], sa[3][r]));
      v = fmaxf(v, __shfl_xor(v, 1));
      v = fmaxf(v, __shfl_xor(v, 2));
      v = fmaxf(v, __shfl_xor(v, 4));
      v = fmaxf(v, __shfl_xor(v, 8));
      float mn = fmaxf(mrow[r], v * SCALE_);
      alpha[r] = __expf(mrow[r] - mn);
      mrow[r] = mn;
    }
    float rs[4] = {0.f, 0.f, 0.f, 0.f};
    __bf16* pw = &Pl[wid][0];
#pragma unroll
    for (int n = 0; n < 4; n++) {
#pragma unroll
      for (int r = 0; r < 4; r++) {
        float p = __expf(sa[n][r] * SCALE_ - mrow[r]);
        rs[r] += p;
        int q = g * 4 + r;
        *(__bf16*)((char*)pw + q * 128 + ((n * 32 + lr * 2) ^ (((q >> 2) & 3) << 4))) = (__bf16)p;
      }
    }
#pragma unroll
    for (int r = 0; r < 4; r++) {
      float v = rs[r];
      v += __shfl_xor(v, 1);
      v += __shfl_xor(v, 2);
      v += __shfl_xor(v, 4);
      v += __shfl_xor(v, 8);
      lrow[r] = lrow[r] * alpha[r] + v;
    }
#pragma unroll
    for (int df = 0; df < 4; df++)
#pragma unroll
      for (int r = 0; r < 4; r++) po[df][r] *= alpha[r];

    // P writes must be visible to this wave's fragment reads (per-wave region, no barrier)
    asm volatile("s_waitcnt lgkmcnt(0)" ::: "memory");

    bf16x8 pa[2];
#pragma unroll
    for (int ks = 0; ks < 2; ks++)
      pa[ks] = *(const bf16x8*)((const char*)pw + lr * 128 + ((ks * 64 + g * 16) ^ (((lr >> 2) & 3) << 4)));
#pragma unroll
    for (int df = 0; df < 4; df++) {
#pragma unroll
      for (int ks = 0; ks < 2; ks++) {
        int d = df * 16 + lr;
        bf16x8 vf = *(const bf16x8*)((const char*)Vl + d * 128 + ((ks * 64 + g * 16) ^ ((d & 7) << 4)));
        po[df] = mfma16(pa[ks], vf, po[df]);
      }
    }
  }

  // epilogue: O / l
#pragma unroll
  for (int r = 0; r < 4; r++) {
    float inv = 1.0f / lrow[r];
    size_t row = (size_t)(b * NQ_ + qbase + g * 4 + r);
#pragma unroll
    for (int df = 0; df < 4; df++) {
      AO[row * 1024 + h * 64 + df * 16 + lr] = (__bf16)(po[df][r] * inv);
    }
  }
}

extern "C" void kernel_launch(void* const* d_in, const int* in_sizes, int n_in,
                              void* d_out, int out_size, void* d_ws, size_t ws_size,
                              hipStream_t stream) {
  (void)in_sizes; (void)n_in; (void)out_size; (void)ws_size;
  const float* x_q  = (const float*)d_in[0];
  const float* x_kv = (const float*)d_in[1];
  const float* Wq   = (const float*)d_in[2];
  const float* bq   = (const float*)d_in[3];
  const float* Wkv  = (const float*)d_in[4];
  const float* bkv  = (const float*)d_in[5];
  const float* Wp   = (const float*)d_in[6];
  const float* bp   = (const float*)d_in[7];

  char* w = (char*)d_ws;
  __bf16* xq_bf  = (__bf16*)w; w += (size_t)8388608 * 2;   // [8192][1024]
  __bf16* xkv_bf = (__bf16*)w; w += (size_t)8388608 * 2;   // [8192][1024]
  __bf16* Wq_t   = (__bf16*)w; w += (size_t)1048576 * 2;   // [1024][1024]
  __bf16* Wkv_t  = (__bf16*)w; w += (size_t)2097152 * 2;   // [2048][1024]
  __bf16* Wp_t   = (__bf16*)w; w += (size_t)1048576 * 2;   // [1024][1024]
  __bf16* Q_bf   = (__bf16*)w; w += (size_t)8388608 * 2;   // [8192][1024]
  __bf16* KV_bf  = (__bf16*)w; w += (size_t)16777216 * 2;  // [8192][2048]
  __bf16* Vt     = (__bf16*)w; w += (size_t)8388608 * 2;   // [64*64][2048]
  __bf16* AO     = (__bf16*)w; w += (size_t)8388608 * 2;   // [8192][1024]

  cvt_bf16_k<<<8192, 256, 0, stream>>>(x_q, xq_bf, 8388608);
  cvt_bf16_k<<<8192, 256, 0, stream>>>(x_kv, xkv_bf, 8388608);
  transpose_cvt_k<<<dim3(32, 32), dim3(32, 8), 0, stream>>>(Wq, Wq_t, 1024, 1024);
  transpose_cvt_k<<<dim3(64, 32), dim3(32, 8), 0, stream>>>(Wkv, Wkv_t, 1024, 2048);
  transpose_cvt_k<<<dim3(32, 32), dim3(32, 8), 0, stream>>>(Wp, Wp_t, 1024, 1024);

  gemm_bt_k<true, false><<<dim3(8, 64), 256, 0, stream>>>(xq_bf, Wq_t, bq, nullptr, Q_bf, 8192, 1024, 1024);
  gemm_bt_k<true, false><<<dim3(16, 64), 256, 0, stream>>>(xkv_bf, Wkv_t, bkv, nullptr, KV_bf, 8192, 2048, 1024);
  reorder_v_k<<<dim3(32, 64), 256, 0, stream>>>(KV_bf, Vt);
  attn_k<<<dim3(32, 64), 256, 0, stream>>>(Q_bf, KV_bf, Vt, AO);
  gemm_bt_k<false, true><<<dim3(8, 64), 256, 0, stream>>>(AO, Wp_t, bp, x_q, d_out, 8192, 1024, 1024);
}